// Round 8
// baseline (363.272 us; speedup 1.0000x reference)
//
#include <hip/hip_runtime.h>
#include <hip/hip_bf16.h>
#include <math.h>

#define T_TOK 2048
#define DIM 512
#define HID 1024
#define NE 8
#define CAP 1024   // per-expert pair capacity (actual ~512 at seed-0 routing)

#define GRID 512        // 2/CU worst case, 3/CU measured -> all co-resident, no deadlock
#define ROUT_BLKS 128
#define CAST_BLKS (GRID - ROUT_BLKS)   // 384
#define G1_TILES (NE * 16 * 8)         // 1024
#define G2_TILES (NE * 16 * 2 * 4)     // 1024

typedef __attribute__((ext_vector_type(8))) short short8;
typedef __attribute__((ext_vector_type(4))) float floatx4;

__device__ __forceinline__ unsigned short f2bf_bits(float f) {
    __hip_bfloat16 h = __float2bfloat16(f);
    return *reinterpret_cast<unsigned short*>(&h);
}

__device__ __forceinline__ float bf2f(unsigned short u) {
    unsigned int b = ((unsigned int)u) << 16;
    return *reinterpret_cast<float*>(&b);
}

// async global->LDS: 64 lanes x 16B = 1 KB; LDS dst = wave-uniform base + lane*16
__device__ __forceinline__ void gl2lds(const unsigned short* g, unsigned short* l) {
    __builtin_amdgcn_global_load_lds(
        (const __attribute__((address_space(1))) unsigned int*)g,
        (__attribute__((address_space(3))) unsigned int*)l, 16, 0, 0);
}

// LDS frag read: packed [row][128] shorts (BK=128), 16-B granule kg of row r
// stored at kg^(r&7) (XOR permutes low 3 bits within each 8-granule half)
__device__ __forceinline__ short8 frag(const unsigned short* s, int row, int kg) {
    return *reinterpret_cast<const short8*>(s + row * 128 + (((kg) ^ (row & 7)) << 3));
}

// stage T rows (k-slice of 128 = 256 B/row) from row-major global into packed
// swizzled LDS; one gl2lds covers 4 rows (lane>>4) x 16 granules (lane&15)
template<int T>
__device__ __forceinline__ void stage_tile(const unsigned short* src, size_t RS,
                                           int k0, unsigned short* lds,
                                           int wave, int lane) {
    int ro = lane >> 4, gr = lane & 15;
#pragma unroll
    for (int i = wave; i < T / 4; i += 4) {
        int r = i * 4 + ro;
        gl2lds(src + (size_t)r * RS + k0 + (((gr ^ (r & 7)) << 3)),
               lds + i * 512);
    }
}

// coarse grid barrier: one arrive-atomic per block, tid0 spins, no per-tile deps.
// Safe because all GRID blocks are co-resident (grid 512 <= capacity 768).
__device__ __forceinline__ void gbar(int* ctr, int target) {
    __syncthreads();
    if (threadIdx.x == 0) {
        __threadfence();   // release: publish this block's writes
        __hip_atomic_fetch_add(ctr, 1, __ATOMIC_RELEASE, __HIP_MEMORY_SCOPE_AGENT);
        while (__hip_atomic_load(ctr, __ATOMIC_RELAXED, __HIP_MEMORY_SCOPE_AGENT) < target)
            __builtin_amdgcn_s_sleep(2);
    }
    __syncthreads();
    __threadfence();       // acquire: invalidate stale cached lines
}

// ---------------- single mega-kernel: 4 phases, 3 grid barriers ----------------
// flags (int* fl = ws, first 4 KB memset to 0 each iteration):
//   fl[0..127] counts (stride 16 per expert)
//   fl[128] q1 (gemm1 tile queue)   fl[129] q2 (gemm2 tile queue)
//   fl[160] bar1   fl[192] bar2   fl[224] bar3
__global__ __launch_bounds__(256, 3)
void moe_mega(const float* __restrict__ x, const float* __restrict__ wr,
              const float* __restrict__ br, const float* __restrict__ w1,
              const float* __restrict__ w2,
              unsigned short* __restrict__ w1b, unsigned short* __restrict__ w2b,
              unsigned short* __restrict__ xg, int* __restrict__ fl,
              int2* __restrict__ pairSlot, float2* __restrict__ pw,
              unsigned short* __restrict__ Hb, unsigned short* __restrict__ ybuf,
              float* __restrict__ out, float* __restrict__ logits_out) {
    __shared__ __align__(16) unsigned short s_a[64 * 128];    // 16 KB
    __shared__ __align__(16) unsigned short s_b[128 * 128];   // 32 KB
    __shared__ int s_next;

    const int bx = blockIdx.x, tid = threadIdx.x;
    const int wave = tid >> 6, lane = tid & 63;
    const int g = lane >> 4, ln = lane & 15;
    const int wm = wave & 1, wn = wave >> 1;

    int* counts = fl;
    int* q1   = fl + 128;
    int* q2   = fl + 129;
    int* bar1 = fl + 160;
    int* bar2 = fl + 192;
    int* bar3 = fl + 224;

    // ---- phase 1: router (blocks 0..127) | weight cast (blocks 128..511) ----
    if (bx < ROUT_BLKS) {
        for (int it = 0; it < 4; it++) {
            int t = bx * 16 + it * 4 + wave;
            const float4* xr = reinterpret_cast<const float4*>(x + (size_t)t * DIM);
            float4 xa = xr[lane * 2], xc = xr[lane * 2 + 1];
            short8 o;
            o[0] = (short)f2bf_bits(xa.x); o[1] = (short)f2bf_bits(xa.y);
            o[2] = (short)f2bf_bits(xa.z); o[3] = (short)f2bf_bits(xa.w);
            o[4] = (short)f2bf_bits(xc.x); o[5] = (short)f2bf_bits(xc.y);
            o[6] = (short)f2bf_bits(xc.z); o[7] = (short)f2bf_bits(xc.w);
            float p[NE];
#pragma unroll
            for (int e = 0; e < NE; e++) {
                const float4* wre = reinterpret_cast<const float4*>(wr + e * DIM);
                float4 wa = wre[lane * 2], wc = wre[lane * 2 + 1];
                p[e] = xa.x * wa.x + xa.y * wa.y + xa.z * wa.z + xa.w * wa.w
                     + xc.x * wc.x + xc.y * wc.y + xc.z * wc.z + xc.w * wc.w;
            }
#pragma unroll
            for (int e = 0; e < NE; e++) {
#pragma unroll
                for (int off = 32; off >= 1; off >>= 1)
                    p[e] += __shfl_xor(p[e], off, 64);
            }
            int slot1 = 0, slot2 = 0;
            if (lane == 0) {
                float l[NE];
#pragma unroll
                for (int e = 0; e < NE; e++) {
                    l[e] = p[e] + br[e];
                    logits_out[(size_t)t * NE + e] = l[e];
                }
                int e1 = 0;
#pragma unroll
                for (int e = 1; e < NE; e++) if (l[e] > l[e1]) e1 = e;
                int es = -1;
#pragma unroll
                for (int e = 0; e < NE; e++) {
                    if (e == e1) continue;
                    if (es < 0 || l[e] > l[es]) es = e;
                }
                float z = expf(l[es] - l[e1]);
                float inv = 1.f / (1.f + z);
                int pos1 = atomicAdd(&counts[e1 * 16], 1);
                if (pos1 > CAP - 1) pos1 = CAP - 1;
                int pos2 = atomicAdd(&counts[es * 16], 1);
                if (pos2 > CAP - 1) pos2 = CAP - 1;
                slot1 = e1 * CAP + pos1;
                slot2 = es * CAP + pos2;
                pairSlot[t] = make_int2(slot1, slot2);
                pw[t] = make_float2(inv, z * inv);
            }
            slot1 = __shfl(slot1, 0);
            slot2 = __shfl(slot2, 0);
            *reinterpret_cast<short8*>(xg + (size_t)slot1 * DIM + lane * 8) = o;
            *reinterpret_cast<short8*>(xg + (size_t)slot2 * DIM + lane * 8) = o;
        }
    } else {
        // weight cast: w1 then w2, 2*1048576 float4, block-stride over 384 blocks
        const int n1 = NE * HID * DIM / 4;
        for (int i = (bx - ROUT_BLKS) * 256 + tid; i < 2 * n1; i += CAST_BLKS * 256) {
            const float* s = (i < n1) ? w1 : w2;
            unsigned short* d = (i < n1) ? w1b : w2b;
            int j = (i < n1) ? i : i - n1;
            float4 v = reinterpret_cast<const float4*>(s)[j];
            ushort4 o;
            o.x = f2bf_bits(v.x); o.y = f2bf_bits(v.y);
            o.z = f2bf_bits(v.z); o.w = f2bf_bits(v.w);
            reinterpret_cast<ushort4*>(d)[j] = o;
        }
    }
    gbar(bar1, GRID);

    // ---- phase 2: GEMM1  H = gelu(Xg @ W1^T); work-stealing queue over 1024 tiles ----
    while (true) {
        if (tid == 0)
            s_next = __hip_atomic_fetch_add(q1, 1, __ATOMIC_RELAXED, __HIP_MEMORY_SCOPE_AGENT);
        __syncthreads();
        int t5 = s_next;
        if (t5 >= G1_TILES) break;
        int e = t5 & 7;
        int rest = t5 >> 3;
        int n0 = (rest & 7) * 128;
        int m0 = (rest >> 3) * 64;
        int cnt = counts[e * 16]; if (cnt > CAP) cnt = CAP;
        if (m0 < cnt) {
            const unsigned short* asrc = xg + (size_t)(e * CAP + m0) * DIM;
            const unsigned short* bsrc = w1b + (size_t)(e * HID + n0) * DIM;
            floatx4 acc[2][4];
#pragma unroll
            for (int mf = 0; mf < 2; mf++)
#pragma unroll
                for (int nf = 0; nf < 4; nf++) acc[mf][nf] = (floatx4){0.f, 0.f, 0.f, 0.f};
            for (int ph = 0; ph < 4; ph++) {
                int k0 = ph * 128;
                stage_tile<64>(asrc, DIM, k0, s_a, wave, lane);
                stage_tile<128>(bsrc, DIM, k0, s_b, wave, lane);
                __syncthreads();
#pragma unroll
                for (int ks = 0; ks < 4; ks++) {
                    short8 a0 = frag(s_a, wm * 32 + ln, ks * 4 + g);
                    short8 a1 = frag(s_a, wm * 32 + 16 + ln, ks * 4 + g);
#pragma unroll
                    for (int nf = 0; nf < 4; nf++) {
                        short8 b = frag(s_b, wn * 64 + nf * 16 + ln, ks * 4 + g);
                        acc[0][nf] = __builtin_amdgcn_mfma_f32_16x16x32_bf16(a0, b, acc[0][nf], 0, 0, 0);
                        acc[1][nf] = __builtin_amdgcn_mfma_f32_16x16x32_bf16(a1, b, acc[1][nf], 0, 0, 0);
                    }
                }
                __syncthreads();
            }
#pragma unroll
            for (int mf = 0; mf < 2; mf++)
#pragma unroll
                for (int nf = 0; nf < 4; nf++)
#pragma unroll
                    for (int r = 0; r < 4; r++) {
                        int lr = wm * 32 + mf * 16 + g * 4 + r;
                        int col = n0 + wn * 64 + nf * 16 + ln;
                        float v = acc[mf][nf][r];
                        float gv = 0.5f * v * (1.f + erff(v * 0.70710678118f));
                        Hb[(size_t)(e * CAP + m0 + lr) * HID + col] = f2bf_bits(gv);
                    }
        }
        __syncthreads();   // protect s_next before next grab
    }
    gbar(bar2, GRID);

    // ---- phase 3: GEMM2  ybuf[kv] = H @ W2^T (bf16); queue over 1024 tiles ----
    while (true) {
        if (tid == 0)
            s_next = __hip_atomic_fetch_add(q2, 1, __ATOMIC_RELAXED, __HIP_MEMORY_SCOPE_AGENT);
        __syncthreads();
        int t6 = s_next;
        if (t6 >= G2_TILES) break;
        int e = t6 & 7;
        int rest = t6 >> 3;
        int n0 = (rest & 3) * 128;
        int kv = (rest >> 2) & 1;
        int m0 = (rest >> 3) * 64;
        int cnt = counts[e * 16]; if (cnt > CAP) cnt = CAP;
        if (m0 < cnt) {
            const unsigned short* asrc = Hb + (size_t)(e * CAP + m0) * HID;
            const unsigned short* bsrc = w2b + (size_t)(e * DIM + n0) * HID;
            floatx4 acc[2][4];
#pragma unroll
            for (int mf = 0; mf < 2; mf++)
#pragma unroll
                for (int nf = 0; nf < 4; nf++) acc[mf][nf] = (floatx4){0.f, 0.f, 0.f, 0.f};
            for (int ph = 0; ph < 4; ph++) {
                int k0 = kv * 512 + ph * 128;
                stage_tile<64>(asrc, HID, k0, s_a, wave, lane);
                stage_tile<128>(bsrc, HID, k0, s_b, wave, lane);
                __syncthreads();
#pragma unroll
                for (int ks = 0; ks < 4; ks++) {
                    short8 a0 = frag(s_a, wm * 32 + ln, ks * 4 + g);
                    short8 a1 = frag(s_a, wm * 32 + 16 + ln, ks * 4 + g);
#pragma unroll
                    for (int nf = 0; nf < 4; nf++) {
                        short8 b = frag(s_b, wn * 64 + nf * 16 + ln, ks * 4 + g);
                        acc[0][nf] = __builtin_amdgcn_mfma_f32_16x16x32_bf16(a0, b, acc[0][nf], 0, 0, 0);
                        acc[1][nf] = __builtin_amdgcn_mfma_f32_16x16x32_bf16(a1, b, acc[1][nf], 0, 0, 0);
                    }
                }
                __syncthreads();
            }
            unsigned short* yb = ybuf + (size_t)kv * (NE * CAP * DIM);
#pragma unroll
            for (int mf = 0; mf < 2; mf++)
#pragma unroll
                for (int nf = 0; nf < 4; nf++)
#pragma unroll
                    for (int r = 0; r < 4; r++) {
                        int lr = wm * 32 + mf * 16 + g * 4 + r;
                        int col = n0 + wn * 64 + nf * 16 + ln;
                        yb[(size_t)(e * CAP + m0 + lr) * DIM + col] = f2bf_bits(acc[mf][nf][r]);
                    }
        }
        __syncthreads();
    }
    gbar(bar3, GRID);

    // ---- phase 4: combine (bf16 ybuf reads, f32 out); exactly 1 id per thread ----
    {
        int id = bx * 256 + tid;   // 131072 = 2048 tokens x 64 groups of 8
        int t = id >> 6, d8 = (id & 63) * 8;
        int2 s = pairSlot[t];
        float2 w = pw[t];
        const size_t KV = (size_t)NE * CAP * DIM;
        short8 a = *reinterpret_cast<const short8*>(ybuf + (size_t)s.x * DIM + d8);
        short8 b = *reinterpret_cast<const short8*>(ybuf + KV + (size_t)s.x * DIM + d8);
        short8 c = *reinterpret_cast<const short8*>(ybuf + (size_t)s.y * DIM + d8);
        short8 d = *reinterpret_cast<const short8*>(ybuf + KV + (size_t)s.y * DIM + d8);
        float4 r0, r1;
#pragma unroll
        for (int j = 0; j < 8; j++) {
            float v = w.x * (bf2f((unsigned short)a[j]) + bf2f((unsigned short)b[j]))
                    + w.y * (bf2f((unsigned short)c[j]) + bf2f((unsigned short)d[j]));
            if (j < 4) (&r0.x)[j] = v; else (&r1.x)[j - 4] = v;
        }
        float4* dst = reinterpret_cast<float4*>(out + (size_t)t * DIM + d8);
        dst[0] = r0;
        dst[1] = r1;
    }
}

extern "C" void kernel_launch(void* const* d_in, const int* in_sizes, int n_in,
                              void* d_out, int out_size, void* d_ws, size_t ws_size,
                              hipStream_t stream) {
    const float* x  = (const float*)d_in[0];
    const float* wr = (const float*)d_in[1];
    const float* br = (const float*)d_in[2];
    const float* w1 = (const float*)d_in[3];
    const float* w2 = (const float*)d_in[4];
    float* out = (float*)d_out;
    float* logits_out = out + (size_t)T_TOK * DIM;

    char* ws = (char*)d_ws;
    int*    fl       = (int*)ws;                                // 4 KB flags/queues/barriers
    int2*   pairSlot = (int2*)(ws + 4096);                      // 16 KB
    float2* pw       = (float2*)(ws + 24576);                   // 16 KB
    unsigned short* xg  = (unsigned short*)(ws + 131072);       // 8.4 MB
    unsigned short* w1b = (unsigned short*)(ws + 8519680);      // 8.4 MB
    unsigned short* w2b = (unsigned short*)(ws + 16908288);     // 8.4 MB
    unsigned short* Hb  = (unsigned short*)(ws + 25296896);     // 16.8 MB
    unsigned short* ybuf = (unsigned short*)(ws + 42074112);    // 16.8 MB bf16 (2 kv halves)

    hipMemsetAsync(fl, 0, 4096, stream);

    moe_mega<<<GRID, 256, 0, stream>>>(
        x, wr, br, w1, w2, w1b, w2b, xg, fl, pairSlot, pw, Hb, ybuf,
        out, logits_out);
}

// Round 9
// 127.096 us; speedup vs baseline: 2.8582x; 2.8582x over previous
//
#include <hip/hip_runtime.h>
#include <hip/hip_bf16.h>
#include <math.h>

#define T_TOK 2048
#define DIM 512
#define HID 1024
#define NE 8
#define CAP 1024   // per-expert pair capacity (actual ~512 at seed-0 routing)

#define ROUT_BLKS 128
#define CAST_BLKS 2048   // 2*1048576 float4 / (256 thr * 4 per thread)

typedef __attribute__((ext_vector_type(8))) short short8;
typedef __attribute__((ext_vector_type(4))) float floatx4;

__device__ __forceinline__ unsigned short f2bf_bits(float f) {
    __hip_bfloat16 h = __float2bfloat16(f);
    return *reinterpret_cast<unsigned short*>(&h);
}

__device__ __forceinline__ float bf2f(unsigned short u) {
    unsigned int b = ((unsigned int)u) << 16;
    return *reinterpret_cast<float*>(&b);
}

// async global->LDS: 64 lanes x 16B = 1 KB; LDS dst = wave-uniform base + lane*16
__device__ __forceinline__ void gl2lds(const unsigned short* g, unsigned short* l) {
    __builtin_amdgcn_global_load_lds(
        (const __attribute__((address_space(1))) unsigned int*)g,
        (__attribute__((address_space(3))) unsigned int*)l, 16, 0, 0);
}

// LDS frag read: packed [row][128] shorts (BK=128), 16-B granule kg of row r
// stored at kg^(r&7) (XOR permutes low 3 bits within each 8-granule half)
__device__ __forceinline__ short8 frag(const unsigned short* s, int row, int kg) {
    return *reinterpret_cast<const short8*>(s + row * 128 + (((kg) ^ (row & 7)) << 3));
}

// stage T rows (k-slice of 128 = 256 B/row) from row-major global into packed
// swizzled LDS; one gl2lds covers 4 rows (lane>>4) x 16 granules (lane&15)
template<int T>
__device__ __forceinline__ void stage_tile(const unsigned short* src, size_t RS,
                                           int k0, unsigned short* lds,
                                           int wave, int lane) {
    int ro = lane >> 4, gr = lane & 15;
#pragma unroll
    for (int i = wave; i < T / 4; i += 4) {
        int r = i * 4 + ro;
        gl2lds(src + (size_t)r * RS + k0 + (((gr ^ (r & 7)) << 3)),
               lds + i * 512);
    }
}

// ---------------- prep: router+gather (blocks 0..127) | weight cast ----------------
__global__ __launch_bounds__(256)
void prep(const float* __restrict__ x, const float* __restrict__ wr,
          const float* __restrict__ br,
          const float* __restrict__ w1, const float* __restrict__ w2,
          unsigned short* __restrict__ w1b, unsigned short* __restrict__ w2b,
          unsigned short* __restrict__ xg, int* __restrict__ counts,
          int2* __restrict__ pairSlot, float2* __restrict__ pw,
          float* __restrict__ logits_out) {
    int bx = blockIdx.x;
    int tid = threadIdx.x;
    if (bx >= ROUT_BLKS) {
        // weight cast: 4 float4 per thread
        const int n1 = NE * HID * DIM / 4;
        int base = (bx - ROUT_BLKS) * 1024 + tid;
#pragma unroll
        for (int rep = 0; rep < 4; rep++) {
            int i = base + rep * 256;
            const float* s = (i < n1) ? w1 : w2;
            unsigned short* d = (i < n1) ? w1b : w2b;
            int j = (i < n1) ? i : i - n1;
            float4 v = reinterpret_cast<const float4*>(s)[j];
            ushort4 o;
            o.x = f2bf_bits(v.x); o.y = f2bf_bits(v.y);
            o.z = f2bf_bits(v.z); o.w = f2bf_bits(v.w);
            reinterpret_cast<ushort4*>(d)[j] = o;
        }
        return;
    }
    // router: 128 blocks x 16 tokens; wave per token, 4 iterations
    int wave = tid >> 6, lane = tid & 63;
    for (int it = 0; it < 4; it++) {
        int t = bx * 16 + it * 4 + wave;
        const float4* xr = reinterpret_cast<const float4*>(x + (size_t)t * DIM);
        float4 xa = xr[lane * 2], xc = xr[lane * 2 + 1];
        short8 o;
        o[0] = (short)f2bf_bits(xa.x); o[1] = (short)f2bf_bits(xa.y);
        o[2] = (short)f2bf_bits(xa.z); o[3] = (short)f2bf_bits(xa.w);
        o[4] = (short)f2bf_bits(xc.x); o[5] = (short)f2bf_bits(xc.y);
        o[6] = (short)f2bf_bits(xc.z); o[7] = (short)f2bf_bits(xc.w);
        float p[NE];
#pragma unroll
        for (int e = 0; e < NE; e++) {
            const float4* wre = reinterpret_cast<const float4*>(wr + e * DIM);
            float4 wa = wre[lane * 2], wc = wre[lane * 2 + 1];
            p[e] = xa.x * wa.x + xa.y * wa.y + xa.z * wa.z + xa.w * wa.w
                 + xc.x * wc.x + xc.y * wc.y + xc.z * wc.z + xc.w * wc.w;
        }
#pragma unroll
        for (int e = 0; e < NE; e++) {
#pragma unroll
            for (int off = 32; off >= 1; off >>= 1)
                p[e] += __shfl_xor(p[e], off, 64);
        }
        int slot1 = 0, slot2 = 0;
        if (lane == 0) {
            float l[NE];
#pragma unroll
            for (int e = 0; e < NE; e++) {
                l[e] = p[e] + br[e];
                logits_out[(size_t)t * NE + e] = l[e];
            }
            int e1 = 0;
#pragma unroll
            for (int e = 1; e < NE; e++) if (l[e] > l[e1]) e1 = e;
            int es = -1;
#pragma unroll
            for (int e = 0; e < NE; e++) {
                if (e == e1) continue;
                if (es < 0 || l[e] > l[es]) es = e;
            }
            float z = expf(l[es] - l[e1]);
            float inv = 1.f / (1.f + z);
            int pos1 = atomicAdd(&counts[e1 * 16], 1);
            if (pos1 > CAP - 1) pos1 = CAP - 1;
            int pos2 = atomicAdd(&counts[es * 16], 1);
            if (pos2 > CAP - 1) pos2 = CAP - 1;
            slot1 = e1 * CAP + pos1;
            slot2 = es * CAP + pos2;
            pairSlot[t] = make_int2(slot1, slot2);
            pw[t] = make_float2(inv, z * inv);
        }
        slot1 = __shfl(slot1, 0);
        slot2 = __shfl(slot2, 0);
        *reinterpret_cast<short8*>(xg + (size_t)slot1 * DIM + lane * 8) = o;
        *reinterpret_cast<short8*>(xg + (size_t)slot2 * DIM + lane * 8) = o;
    }
}

// ---------------- GEMM1: H = gelu(Xg @ W1^T), per expert ----------------
// Block 64m x 64n, K=512 in 4 phases of BK=128. 4 waves (2x2), 32 KB LDS.
// Smaller tile -> 2x grid (1024 active blocks = 4/CU) to fix occupancy
// starvation at these small per-expert shapes.
__global__ __launch_bounds__(256, 4)
void gemm1(const unsigned short* __restrict__ xg,
           const unsigned short* __restrict__ w1b,
           const int* __restrict__ counts,
           unsigned short* __restrict__ Hb) {
    int bx = blockIdx.x;
    int e = bx & 7;                       // XCD affinity
    int rest = bx >> 3;
    int n0 = (rest & 15) * 64;            // 16 n-blocks (HID/64)
    int m0 = (rest >> 4) * 64;            // 16 m-blocks (CAP/64)
    int cnt = counts[e * 16]; if (cnt > CAP) cnt = CAP;
    if (m0 >= cnt) return;

    __shared__ __align__(16) unsigned short s_a[64 * 128];    // 16 KB
    __shared__ __align__(16) unsigned short s_b[64 * 128];    // 16 KB

    int tid = threadIdx.x, wave = tid >> 6, lane = tid & 63;
    int g = lane >> 4, ln = lane & 15;
    int wm = wave & 1, wn = wave >> 1;

    const unsigned short* asrc = xg + (size_t)(e * CAP + m0) * DIM;
    const unsigned short* bsrc = w1b + (size_t)(e * HID + n0) * DIM;

    floatx4 acc[2][2];
#pragma unroll
    for (int mf = 0; mf < 2; mf++)
#pragma unroll
        for (int nf = 0; nf < 2; nf++) acc[mf][nf] = (floatx4){0.f, 0.f, 0.f, 0.f};

    for (int ph = 0; ph < 4; ph++) {
        int k0 = ph * 128;
        stage_tile<64>(asrc, DIM, k0, s_a, wave, lane);
        stage_tile<64>(bsrc, DIM, k0, s_b, wave, lane);
        __syncthreads();
#pragma unroll
        for (int ks = 0; ks < 4; ks++) {
            short8 a0 = frag(s_a, wm * 32 + ln, ks * 4 + g);
            short8 a1 = frag(s_a, wm * 32 + 16 + ln, ks * 4 + g);
#pragma unroll
            for (int nf = 0; nf < 2; nf++) {
                short8 b = frag(s_b, wn * 32 + nf * 16 + ln, ks * 4 + g);
                acc[0][nf] = __builtin_amdgcn_mfma_f32_16x16x32_bf16(a0, b, acc[0][nf], 0, 0, 0);
                acc[1][nf] = __builtin_amdgcn_mfma_f32_16x16x32_bf16(a1, b, acc[1][nf], 0, 0, 0);
            }
        }
        __syncthreads();
    }
#pragma unroll
    for (int mf = 0; mf < 2; mf++)
#pragma unroll
        for (int nf = 0; nf < 2; nf++)
#pragma unroll
            for (int r = 0; r < 4; r++) {
                int lr = wm * 32 + mf * 16 + g * 4 + r;
                int col = n0 + wn * 32 + nf * 16 + ln;
                float v = acc[mf][nf][r];
                float gv = 0.5f * v * (1.f + erff(v * 0.70710678118f));
                Hb[(size_t)(e * CAP + m0 + lr) * HID + col] = f2bf_bits(gv);
            }
}

// ---------------- GEMM2: ybuf[kv] = H @ W2^T, stored as bf16 ----------------
// Block 64m x 64n, kv-split (two K halves of 512, 4 phases each), 32 KB LDS.
__global__ __launch_bounds__(256, 4)
void gemm2(const unsigned short* __restrict__ Hb,
           const unsigned short* __restrict__ w2b,
           const int* __restrict__ counts,
           unsigned short* __restrict__ ybuf) {
    int bx = blockIdx.x;
    int e = bx & 7;
    int rest = bx >> 3;
    int n0 = (rest & 7) * 64;             // 8 n-blocks (DIM/64)
    int kv = (rest >> 3) & 1;
    int m0 = (rest >> 4) * 64;            // 16 m-blocks
    int cnt = counts[e * 16]; if (cnt > CAP) cnt = CAP;
    if (m0 >= cnt) return;

    __shared__ __align__(16) unsigned short s_a[64 * 128];
    __shared__ __align__(16) unsigned short s_b[64 * 128];

    int tid = threadIdx.x, wave = tid >> 6, lane = tid & 63;
    int g = lane >> 4, ln = lane & 15;
    int wm = wave & 1, wn = wave >> 1;

    const unsigned short* asrc = Hb + (size_t)(e * CAP + m0) * HID;
    const unsigned short* bsrc = w2b + (size_t)(e * DIM + n0) * HID;

    floatx4 acc[2][2];
#pragma unroll
    for (int mf = 0; mf < 2; mf++)
#pragma unroll
        for (int nf = 0; nf < 2; nf++) acc[mf][nf] = (floatx4){0.f, 0.f, 0.f, 0.f};

    for (int ph = 0; ph < 4; ph++) {
        int k0 = kv * 512 + ph * 128;
        stage_tile<64>(asrc, HID, k0, s_a, wave, lane);
        stage_tile<64>(bsrc, HID, k0, s_b, wave, lane);
        __syncthreads();
#pragma unroll
        for (int ks = 0; ks < 4; ks++) {
            short8 a0 = frag(s_a, wm * 32 + ln, ks * 4 + g);
            short8 a1 = frag(s_a, wm * 32 + 16 + ln, ks * 4 + g);
#pragma unroll
            for (int nf = 0; nf < 2; nf++) {
                short8 b = frag(s_b, wn * 32 + nf * 16 + ln, ks * 4 + g);
                acc[0][nf] = __builtin_amdgcn_mfma_f32_16x16x32_bf16(a0, b, acc[0][nf], 0, 0, 0);
                acc[1][nf] = __builtin_amdgcn_mfma_f32_16x16x32_bf16(a1, b, acc[1][nf], 0, 0, 0);
            }
        }
        __syncthreads();
    }
    unsigned short* yb = ybuf + (size_t)kv * (NE * CAP * DIM);
#pragma unroll
    for (int mf = 0; mf < 2; mf++)
#pragma unroll
        for (int nf = 0; nf < 2; nf++)
#pragma unroll
            for (int r = 0; r < 4; r++) {
                int lr = wm * 32 + mf * 16 + g * 4 + r;
                int col = n0 + wn * 32 + nf * 16 + ln;
                yb[(size_t)(e * CAP + m0 + lr) * DIM + col] = f2bf_bits(acc[mf][nf][r]);
            }
}

// ---------------- combine (bf16 ybuf reads, f32 out) ----------------
__global__ __launch_bounds__(256)
void combine_kernel(const unsigned short* __restrict__ ybuf,
                    const int2* __restrict__ pairSlot,
                    const float2* __restrict__ pw, float* __restrict__ out) {
    int id = blockIdx.x * 256 + threadIdx.x;   // 131072 = 2048 tokens x 64 groups of 8
    int t = id >> 6, d8 = (id & 63) * 8;
    int2 s = pairSlot[t];
    float2 w = pw[t];
    const size_t KV = (size_t)NE * CAP * DIM;
    short8 a = *reinterpret_cast<const short8*>(ybuf + (size_t)s.x * DIM + d8);
    short8 b = *reinterpret_cast<const short8*>(ybuf + KV + (size_t)s.x * DIM + d8);
    short8 c = *reinterpret_cast<const short8*>(ybuf + (size_t)s.y * DIM + d8);
    short8 d = *reinterpret_cast<const short8*>(ybuf + KV + (size_t)s.y * DIM + d8);
    float4 r0, r1;
#pragma unroll
    for (int j = 0; j < 8; j++) {
        float v = w.x * (bf2f((unsigned short)a[j]) + bf2f((unsigned short)b[j]))
                + w.y * (bf2f((unsigned short)c[j]) + bf2f((unsigned short)d[j]));
        if (j < 4) (&r0.x)[j] = v; else (&r1.x)[j - 4] = v;
    }
    float4* dst = reinterpret_cast<float4*>(out + (size_t)t * DIM + d8);
    dst[0] = r0;
    dst[1] = r1;
}

extern "C" void kernel_launch(void* const* d_in, const int* in_sizes, int n_in,
                              void* d_out, int out_size, void* d_ws, size_t ws_size,
                              hipStream_t stream) {
    const float* x  = (const float*)d_in[0];
    const float* wr = (const float*)d_in[1];
    const float* br = (const float*)d_in[2];
    const float* w1 = (const float*)d_in[3];
    const float* w2 = (const float*)d_in[4];
    float* out = (float*)d_out;
    float* logits_out = out + (size_t)T_TOK * DIM;

    char* ws = (char*)d_ws;
    int*    counts   = (int*)ws;                                // 512 B (x16 padded)
    int2*   pairSlot = (int2*)(ws + 4096);                      // 16 KB
    float2* pw       = (float2*)(ws + 24576);                   // 16 KB
    unsigned short* xg  = (unsigned short*)(ws + 131072);       // 8.4 MB
    unsigned short* w1b = (unsigned short*)(ws + 8519680);      // 8.4 MB
    unsigned short* w2b = (unsigned short*)(ws + 16908288);     // 8.4 MB
    unsigned short* Hb  = (unsigned short*)(ws + 25296896);     // 16.8 MB
    unsigned short* ybuf = (unsigned short*)(ws + 42074112);    // 16.8 MB bf16 (2 kv halves)

    hipMemsetAsync(counts, 0, 512, stream);

    prep<<<ROUT_BLKS + CAST_BLKS, 256, 0, stream>>>(
        x, wr, br, w1, w2, w1b, w2b, xg, counts, pairSlot, pw, logits_out);

    gemm1<<<NE * 16 * 16, 256, 0, stream>>>(xg, w1b, counts, Hb);

    gemm2<<<NE * 16 * 2 * 8, 256, 0, stream>>>(Hb, w2b, counts, ybuf);

    combine_kernel<<<512, 256, 0, stream>>>(ybuf, pairSlot, pw, out);
}